// Round 5
// baseline (177.710 us; speedup 1.0000x reference)
//
#include <hip/hip_runtime.h>
#include <hip/hip_bf16.h>
#include <stdint.h>

#define B_ 4
#define T_ 8
#define N_ 4096
#define F_ 32
#define BT_ (B_*T_)
#define ROWS_ (B_*N_)
#define CAP_ 128
#define EPS_ 1e-5f
#define NELEM_ (B_*T_*N_*F_)

// ---- workspace layout (float offsets) ----
#define WS_BNP    0                       // 256 * 64 per-block BN partials
#define WS_ROWSUM 16384                   // 4096
#define WS_DEG    (WS_ROWSUM + 4096)      // 4096 (int)
#define WS_FRG    (WS_DEG + 4096)         // 52 frags * 64 lanes * 4 dwords
#define WS_PAIR   (WS_FRG + 52*256)       // 4096*CAP_*2  (idx*F_ as float-bits, val)
#define WS_XA     (WS_PAIR + 4096*CAP_*2) // BT_*N_*F_

typedef float v4f __attribute__((ext_vector_type(4)));
typedef _Float16 half8 __attribute__((ext_vector_type(8)));
union HU { uint32_t u[4]; half8 v; };

__device__ inline float sigm_f(float x) {
  return __builtin_amdgcn_rcpf(1.0f + __expf(-x));
}
__device__ inline uint32_t f16pair(float a, float b) {
  union { _Float16 h; unsigned short s; } x, y;
  x.h = (_Float16)a; y.h = (_Float16)b;
  return (uint32_t)x.s | ((uint32_t)y.s << 16);
}
__device__ inline void sp2(float a0, float a1, uint32_t& hi, uint32_t& lo) {
  _Float16 h0 = (_Float16)a0, h1 = (_Float16)a1;
  float r0 = a0 - (float)h0, r1 = a1 - (float)h1;
  union { _Float16 h; unsigned short s; } u0, u1, v0, v1;
  u0.h = h0; u1.h = h1; v0.h = (_Float16)r0; v1.h = (_Float16)r1;
  hi = (uint32_t)u0.s | ((uint32_t)u1.s << 16);
  lo = (uint32_t)v0.s | ((uint32_t)v1.s << 16);
}

// ---- K1: CSR build, 2 rows/block (blocks 0..2047) + BN partials (2048..2303) ----
__global__ void __launch_bounds__(256)
k_pre(const float* __restrict__ x, const float* __restrict__ A, float* __restrict__ ws) {
  if (blockIdx.x < 2048) {
    int m0 = blockIdx.x * 2;
    __shared__ int cnt[2];
    __shared__ float wsum[4][2];
    if (threadIdx.x < 2) cnt[threadIdx.x] = 0;
    __syncthreads();
    int* deg = (int*)&ws[WS_DEG];
    float2* pair = (float2*)&ws[WS_PAIR];
    const float4* A4 = (const float4*)(A + (size_t)m0 * N_);
    float4 av4[8];
#pragma unroll
    for (int r = 0; r < 2; r++)
#pragma unroll
      for (int i = 0; i < 4; i++) av4[r * 4 + i] = A4[r * 1024 + threadIdx.x + 256 * i];  // 8 in flight
    float lsum[2] = {0.f, 0.f};
#pragma unroll
    for (int r = 0; r < 2; r++)
#pragma unroll
      for (int i = 0; i < 4; i++) {
        float av[4] = {av4[r*4+i].x, av4[r*4+i].y, av4[r*4+i].z, av4[r*4+i].w};
        int nb4 = (threadIdx.x + 256 * i) * 4;
#pragma unroll
        for (int e = 0; e < 4; e++) {
          float a = av[e];
          if (a != 0.0f) {
            int p = atomicAdd(&cnt[r], 1);
            if (p < CAP_) pair[(size_t)(m0 + r) * CAP_ + p] = make_float2(__int_as_float((nb4 + e) * F_), a);
            lsum[r] += a;
          }
        }
      }
#pragma unroll
    for (int r = 0; r < 2; r++) {
      float s = lsum[r];
#pragma unroll
      for (int off = 32; off > 0; off >>= 1) s += __shfl_xor(s, off, 64);
      if ((threadIdx.x & 63) == 0) wsum[threadIdx.x >> 6][r] = s;
    }
    __syncthreads();                     // cnt + wsum final
#pragma unroll
    for (int r = 0; r < 2; r++) {
      int c = cnt[r];
      for (int p = c + threadIdx.x; p < 68; p += 256)   // zero-fill incl. prefetch pad
        pair[(size_t)(m0 + r) * CAP_ + p] = make_float2(__int_as_float(0), 0.0f);
    }
    if (threadIdx.x < 2) {
      int r = threadIdx.x;
      deg[m0 + r] = min(cnt[r], CAP_);
      ws[WS_ROWSUM + m0 + r] = wsum[0][r] + wsum[1][r] + wsum[2][r] + wsum[3][r];
    }
  } else {
    int bnb = blockIdx.x - 2048;
    const float4* x4 = (const float4*)x;
    int tid = bnb * 256 + threadIdx.x;
    float s[4] = {0,0,0,0}, s2[4] = {0,0,0,0};
    for (int i = tid; i < NELEM_ / 4; i += 256 * 256) {
      float4 v = x4[i];
      s[0] += v.x; s2[0] += v.x * v.x;
      s[1] += v.y; s2[1] += v.y * v.y;
      s[2] += v.z; s2[2] += v.z * v.z;
      s[3] += v.w; s2[3] += v.w * v.w;
    }
    __shared__ float ls[256][4], ls2[256][4];
#pragma unroll
    for (int r = 0; r < 4; r++) { ls[threadIdx.x][r] = s[r]; ls2[threadIdx.x][r] = s2[r]; }
    __syncthreads();
    int t = threadIdx.x;
    if (t < 32) {                       // channel c = 4*(q&7)+r
      int g = t >> 2, r = t & 3;
      float a = 0.f;
      for (int q = g; q < 256; q += 8) a += ls[q][r];
      ws[WS_BNP + bnb * 64 + t] = a;
    } else if (t < 64) {
      int cch = t - 32;
      int g = cch >> 2, r = cch & 3;
      float b2 = 0.f;
      for (int q = g; q < 256; q += 8) b2 += ls2[q][r];
      ws[WS_BNP + bnb * 64 + t] = b2;
    }
  }
}

// ---- K2: sparse aggregation, 4 bt streams/block -> 1024 blocks = ONE
//      scheduling round at 4 blocks/CU; 16 gather loads in flight/wave.
//      Fold blocks appended at 1024..1075 (run in straggler tail). ----
#define AGG_STEP(d) { \
    float vv = pv[d]; \
    v4f t0 = pb0[d], t1 = pb1[d], t2 = pb2[d], t3 = pb3[d]; \
    float2 p = pl[row * 69 + k + 4 + d]; \
    int off = __float_as_int(p.x) + fo; \
    pv[d] = p.y; \
    pb0[d] = *(const v4f*)(xb0 + off); \
    pb1[d] = *(const v4f*)(xb1 + off); \
    pb2[d] = *(const v4f*)(xb2 + off); \
    pb3[d] = *(const v4f*)(xb3 + off); \
    acc0 += vv * t0; acc1 += vv * t1; acc2 += vv * t2; acc3 += vv * t3; }

__global__ void __launch_bounds__(256, 4)
k_aggf(const float* __restrict__ x, const float* __restrict__ gamma,
       const float* __restrict__ beta, const float* __restrict__ Wg,
       const float* __restrict__ bg, const float* __restrict__ Wih,
       const float* __restrict__ bih, const float* __restrict__ Whh,
       const float* __restrict__ bhh, float* __restrict__ ws) {
  __shared__ float2 pl[32 * 69];        // 17.7 KB (fold path overlays first 14.1 KB)
  int tid = threadIdx.x;
  if (blockIdx.x >= 1024) {
    // ================= fold path: build fragment fi =================
    float* fs   = (float*)pl;
    float* bnp4 = fs;                    // 256
    float* bns  = fs + 256;              // 64
    float* scl  = fs + 320;              // 32
    float* shf  = fs + 352;              // 32
    float* ps   = fs + 384;              // 32
    float* Wg_s = fs + 416;              // 1024
    float* Wic  = fs + 1440;             // 512  (Wih col-slice [32][16])
    float* Wxc  = fs + 1952;             // 512  (Wx col-slice  [32][16])
    float* UsV  = fs + 2464;             // 32   (Us[16], Vs[16])
    float* Whc  = fs + 2496;             // 512  (Whh col-slice [32][16])
    int fi = blockIdx.x - 1024;
    int mt, kt;
    if (fi < 32)      { mt = fi >> 2;              kt = fi & 3; }
    else if (fi < 40) { mt = 8 + ((fi - 32) >> 1); kt = (fi & 1) ? 3 : 0; }
    else              { int r = fi - 40; mt = 12 + r / 3; kt = 1 + r % 3; }
    int cls = mt >> 2;
    int colbase = (cls < 2) ? mt * 16 : 128 + (mt & 3) * 16;
    // ---- stage phase ----
    if (kt == 1 || kt == 2) {            // Whh rows [(kt-1)*32, (kt-1)*32+32), 16 cols
      for (int e = tid; e < 512; e += 256) {
        int r = e >> 4, cc = e & 15;
        Whc[e] = Whh[(size_t)((kt - 1) * 32 + r) * 192 + colbase + cc];
      }
    } else {                             // kt 0/3: Wg + Wih cols + BNP partial reduce
      ((float4*)Wg_s)[tid] = ((const float4*)Wg)[tid];
      for (int e = tid; e < 512; e += 256) {
        int r = e >> 4, cc = e & 15;
        Wic[e] = Wih[(size_t)r * 192 + colbase + cc];
      }
      int g = tid >> 6, cch = tid & 63;
      float a = 0.f;
      for (int i = 0; i < 64; i++) a += ws[WS_BNP + (size_t)(g + 4 * i) * 64 + cch];
      bnp4[g * 64 + cch] = a;
    }
    __syncthreads();
    if ((kt == 0 || kt == 3) && tid < 64)
      bns[tid] = bnp4[tid] + bnp4[64 + tid] + bnp4[128 + tid] + bnp4[192 + tid];
    __syncthreads();
    if ((kt == 0 || kt == 3) && tid < 32) {
      float cntf = (float)(B_ * T_ * N_);
      float mean = bns[tid] / cntf;
      float var = bns[32 + tid] / cntf - mean * mean;
      float sc = gamma[tid] * rsqrtf(var + EPS_);
      scl[tid] = sc;
      shf[tid] = beta[tid] - mean * sc;
    }
    __syncthreads();
    if (kt == 3 && tid < 32) {
      float acc = 0.f;
#pragma unroll
      for (int f = 0; f < 32; f++) acc += shf[f] * Wg_s[f * 32 + tid];
      ps[tid] = acc;
    }
    __syncthreads();
    if (kt == 0) {                       // Wx col-slice: scale[f] * (Wg row f · Wih col)
      for (int e = tid; e < 512; e += 256) {
        int f = e >> 4, cc = e & 15;
        float acc = 0.f;
#pragma unroll
        for (int m = 0; m < 32; m++) acc += Wg_s[f * 32 + m] * Wic[m * 16 + cc];
        Wxc[e] = scl[f] * acc;
      }
    } else if (kt == 3) {
      if (tid < 16) {
        float au = 0.f;
#pragma unroll
        for (int c2 = 0; c2 < 32; c2++) au += ps[c2] * Wic[c2 * 16 + tid];
        UsV[tid] = au;
      } else if (tid < 32) {
        int cc = tid - 16;
        float av = 0.f;
#pragma unroll
        for (int c2 = 0; c2 < 32; c2++) av += bg[c2] * Wic[c2 * 16 + cc];
        UsV[16 + cc] = av + bih[colbase + cc];
      }
    }
    __syncthreads();
    // ---- pack phase (64 lanes) ----
    if (tid < 64) {
      int L = tid, q = L >> 4, c = L & 15;
      uint32_t* wsu = (uint32_t*)ws;
#pragma unroll
      for (int d = 0; d < 4; d++) {
        float a01[2];
#pragma unroll
        for (int h2 = 0; h2 < 2; h2++) {
          int kk = q * 8 + 2 * d + h2;   // 0..31 within this kt block
          float v;
          if (kt == 0)       v = Wxc[kk * 16 + c];
          else if (kt != 3)  v = Whc[kk * 16 + c];
          else if (kk == 0)  v = (cls == 3) ? 0.f : UsV[c];
          else if (kk == 1)  v = (cls < 2) ? (UsV[16 + c] + bhh[colbase + c])
                                           : (cls == 2 ? UsV[16 + c] : bhh[colbase + c]);
          else               v = 0.f;
          a01[h2] = v;
        }
        wsu[WS_FRG + fi * 256 + L * 4 + d] = f16pair(a01[0], a01[1]);
      }
    }
    return;
  }
  // ================= aggregation path =================
  int bid2 = blockIdx.x;
  int chunk = bid2 & 7;                 // 8 chunks of 4 bt; XCD = blockIdx%8 pins slices
  int mg = bid2 >> 3;                   // [0,128): 32-row group
  int row = tid >> 3, f4 = tid & 7;
  int m = mg * 32 + row;
  const int* deg = (const int*)&ws[WS_DEG];
  const float2* pair = (const float2*)&ws[WS_PAIR];
  for (int qq = tid; qq < 32 * 68; qq += 256) {
    int r = qq / 68, sl = qq - r * 68;
    pl[r * 69 + sl] = pair[(size_t)(mg * 32 + r) * CAP_ + sl];
  }
  __syncthreads();
  int d0 = deg[m];
  int dm = min(d0, 64);
  int bound = dm;                       // wave-uniform max over the wave's 8 rows
  bound = max(bound, __shfl_xor(bound, 8, 64));
  bound = max(bound, __shfl_xor(bound, 16, 64));
  bound = max(bound, __shfl_xor(bound, 32, 64));
  bound = (bound + 3) & ~3;             // mult of 4; slots < 68 valid/zeroed
  int bt0 = chunk * 4;
  const float* xb0 = x + (size_t)bt0 * N_ * F_;
  const float* xb1 = xb0 + N_ * F_;
  const float* xb2 = xb0 + 2 * N_ * F_;
  const float* xb3 = xb0 + 3 * N_ * F_;
  int fo = f4 * 4;
  v4f acc0 = {0,0,0,0}, acc1 = {0,0,0,0}, acc2 = {0,0,0,0}, acc3 = {0,0,0,0};
  v4f pb0[4], pb1[4], pb2[4], pb3[4];
  float pv[4];
#pragma unroll
  for (int d = 0; d < 4; d++) {         // prologue: 16 loads in flight
    float2 p = pl[row * 69 + d];
    int off = __float_as_int(p.x) + fo;
    pv[d] = p.y;
    pb0[d] = *(const v4f*)(xb0 + off);
    pb1[d] = *(const v4f*)(xb1 + off);
    pb2[d] = *(const v4f*)(xb2 + off);
    pb3[d] = *(const v4f*)(xb3 + off);
  }
  for (int k = 0; k < bound; k += 4) {
    AGG_STEP(0) AGG_STEP(1) AGG_STEP(2) AGG_STEP(3)
  }
  if (d0 > 64) {                        // statistically never (avg deg ~32)
    for (int k = 64; k < d0; k++) {
      float2 p = pair[(size_t)m * CAP_ + k];
      int off = __float_as_int(p.x) + fo;
      float vv = p.y;
      acc0 += vv * *(const v4f*)(xb0 + off);
      acc1 += vv * *(const v4f*)(xb1 + off);
      acc2 += vv * *(const v4f*)(xb2 + off);
      acc3 += vv * *(const v4f*)(xb3 + off);
    }
  }
  size_t ob = (size_t)bt0 * N_ * F_ + m * F_ + fo;
  *(v4f*)(ws + WS_XA + ob) = acc0;
  *(v4f*)(ws + WS_XA + ob + (size_t)N_ * F_) = acc1;
  *(v4f*)(ws + WS_XA + ob + (size_t)2 * N_ * F_) = acc2;
  *(v4f*)(ws + WS_XA + ob + (size_t)3 * N_ * F_) = acc3;
}

// ---- K4: MFMA GRU, gate-tile split across wave pairs -> 2 waves/SIMD. ----
#define LDA(fi) (*(const half8*)(frg + (fi)*256 + L*4))
#define DO1(A_, fi, BH, BL) { half8 af = LDA(fi); \
  A_ = __builtin_amdgcn_mfma_f32_16x16x32_f16(af, BH, A_, 0, 0, 0); \
  A_ = __builtin_amdgcn_mfma_f32_16x16x32_f16(af, BL, A_, 0, 0, 0); }
#define DO1C(A_, C_, fi, BH, BL) { half8 af = LDA(fi); \
  A_ = __builtin_amdgcn_mfma_f32_16x16x32_f16(af, BH, C_, 0, 0, 0); \
  A_ = __builtin_amdgcn_mfma_f32_16x16x32_f16(af, BL, A_, 0, 0, 0); }

__global__ void __launch_bounds__(256, 2)
k_gru(const float* __restrict__ Wd, const float* __restrict__ bd,
      const float* __restrict__ ws, float* __restrict__ out) {
  __shared__ uint32_t frg[52 * 256];     // 53 KB weight fragments (block-shared)
  __shared__ uint32_t hx[2 * 1344];      // per-GROUP h-exchange, stride 21
  __shared__ float obuf[2][16];          // cross-half output partial
  {
    const uint4* gf = (const uint4*)(ws + WS_FRG);
    uint4* sf = (uint4*)frg;
    for (int i = threadIdx.x; i < 52 * 64; i += 256) sf[i] = gf[i];
  }
  __syncthreads();
  int wid = threadIdx.x >> 6, L = threadIdx.x & 63;
  int grp = wid >> 1, half = wid & 1, h2 = half * 2;
  int q = L >> 4, c = L & 15;
  uint32_t* hxg = hx + grp * 1344;
  int rg0 = blockIdx.x * 32 + grp * 16;  // global row base of this group's 16-row tile
  int b = rg0 >> 12;
  int node0 = rg0 & (N_ - 1);
  // fragment indices for this half's tiles
  int fR0 = 4 * h2, fR1 = 4 * h2 + 4;          // R tiles: mt = h2, h2+1
  int fZ0 = 16 + 4 * h2, fZ1 = 20 + 4 * h2;    // Z tiles: mt = 4+h2, 5+h2
  int fN0 = 32 + 2 * h2, fN1 = 34 + 2 * h2;    // N tiles b0: mt = 8+h2, 9+h2
  int fG0 = 40 + 3 * h2, fG1 = 43 + 3 * h2;    // G tiles b1: mt = 12+h2, 13+h2
  float wdv[2][4];
#pragma unroll
  for (int lg = 0; lg < 2; lg++)
#pragma unroll
    for (int r = 0; r < 4; r++) wdv[lg][r] = Wd[16 * (h2 + lg) + 4 * q + r];
  float bdv = bd[0];

  // ---- b3 fragment (rowsum trick) ----
  HU b3h, b3l;
#pragma unroll
  for (int d = 0; d < 4; d++) { b3h.u[d] = 0; b3l.u[d] = 0; }
  {
    float rsv = ws[WS_ROWSUM + node0 + c];
    uint32_t rhi, rlo;
    sp2(rsv, 1.0f, rhi, rlo);
    if (q == 0) { b3h.u[0] = rhi; b3l.u[0] = rlo & 0xFFFFu; }
  }

  // ---- per-half time-invariant bias tiles (8 v4f) ----
  v4f bias[8];
  {
    v4f z4 = {0.f, 0.f, 0.f, 0.f};
    DO1C(bias[0], z4, fR0 + 3, b3h.v, b3l.v)
    DO1C(bias[1], z4, fR1 + 3, b3h.v, b3l.v)
    DO1C(bias[2], z4, fZ0 + 3, b3h.v, b3l.v)
    DO1C(bias[3], z4, fZ1 + 3, b3h.v, b3l.v)
    DO1C(bias[4], z4, fN0 + 1, b3h.v, b3l.v)
    DO1C(bias[5], z4, fN1 + 1, b3h.v, b3l.v)
    DO1C(bias[6], z4, fG0 + 2, b3h.v, b3l.v)
    DO1C(bias[7], z4, fG1 + 2, b3h.v, b3l.v)
  }

  float h[2][4];
#pragma unroll
  for (int lg = 0; lg < 2; lg++)
#pragma unroll
    for (int r = 0; r < 4; r++) h[lg][r] = 0.f;

  const float* xab = ws + WS_XA;
  size_t xo0 = ((size_t)(b * T_) * N_ + node0 + c) * F_ + q * 8;
  float4 curA = *(const float4*)(xab + xo0);
  float4 curB = *(const float4*)(xab + xo0 + 4);
  float4 nxA, nxB;

#pragma unroll 1
  for (int t = 0; t < T_; t++) {
    // (1) read h fragments packed at end of t-1 (group-shared)
    HU b1h, b1l, b2h, b2l;
    if (t > 0) {
#pragma unroll
      for (int d = 0; d < 4; d++) {
        b1h.u[d] = hxg[((4 * q + d) * 2 + 0) * 21 + c];
        b1l.u[d] = hxg[((4 * q + d) * 2 + 1) * 21 + c];
        b2h.u[d] = hxg[((16 + 4 * q + d) * 2 + 0) * 21 + c];
        b2l.u[d] = hxg[((16 + 4 * q + d) * 2 + 1) * 21 + c];
      }
    }
    __syncthreads();                     // A: all reads done before this step's writes
    // (2) prefetch next xa
    if (t < T_ - 1) {
      size_t xo = ((size_t)(b * T_ + t + 1) * N_ + node0 + c) * F_ + q * 8;
      nxA = *(const float4*)(xab + xo);
      nxB = *(const float4*)(xab + xo + 4);
    }
    // (3) build b0 fragment from current xa
    HU b0h, b0l;
    sp2(curA.x, curA.y, b0h.u[0], b0l.u[0]);
    sp2(curA.z, curA.w, b0h.u[1], b0l.u[1]);
    sp2(curB.x, curB.y, b0h.u[2], b0l.u[2]);
    sp2(curB.z, curB.w, b0h.u[3], b0l.u[3]);
    // (4) MFMAs for this half's 8 tiles
    v4f acc[8];
    if (t > 0) {
      DO1C(acc[0], bias[0], fR0 + 1, b1h.v, b1l.v)
      DO1C(acc[1], bias[1], fR1 + 1, b1h.v, b1l.v)
      DO1C(acc[2], bias[2], fZ0 + 1, b1h.v, b1l.v)
      DO1C(acc[3], bias[3], fZ1 + 1, b1h.v, b1l.v)
      DO1C(acc[6], bias[6], fG0,     b1h.v, b1l.v)
      DO1C(acc[7], bias[7], fG1,     b1h.v, b1l.v)
      DO1(acc[0], fR0 + 2, b2h.v, b2l.v)
      DO1(acc[1], fR1 + 2, b2h.v, b2l.v)
      DO1(acc[2], fZ0 + 2, b2h.v, b2l.v)
      DO1(acc[3], fZ1 + 2, b2h.v, b2l.v)
      DO1(acc[6], fG0 + 1, b2h.v, b2l.v)
      DO1(acc[7], fG1 + 1, b2h.v, b2l.v)
      DO1(acc[0], fR0, b0h.v, b0l.v)
      DO1(acc[1], fR1, b0h.v, b0l.v)
      DO1(acc[2], fZ0, b0h.v, b0l.v)
      DO1(acc[3], fZ1, b0h.v, b0l.v)
      DO1C(acc[4], bias[4], fN0, b0h.v, b0l.v)
      DO1C(acc[5], bias[5], fN1, b0h.v, b0l.v)
    } else {
      DO1C(acc[0], bias[0], fR0, b0h.v, b0l.v)
      DO1C(acc[1], bias[1], fR1, b0h.v, b0l.v)
      DO1C(acc[2], bias[2], fZ0, b0h.v, b0l.v)
      DO1C(acc[3], bias[3], fZ1, b0h.v, b0l.v)
      DO1C(acc[4], bias[4], fN0, b0h.v, b0l.v)
      DO1C(acc[5], bias[5], fN1, b0h.v, b0l.v)
      acc[6] = bias[6]; acc[7] = bias[7];
    }
    // (5) epilogue on this half's 32 hidden dims
    float o = 0.f;
#pragma unroll
    for (int lg = 0; lg < 2; lg++)
#pragma unroll
      for (int r = 0; r < 4; r++) {
        float rr = sigm_f(acc[lg][r]);
        float zz = sigm_f(acc[2 + lg][r]);
        float nn = 2.0f * sigm_f(2.0f * (acc[4 + lg][r] + rr * acc[6 + lg][r])) - 1.0f;
        float hn = zz * (h[lg][r] - nn) + nn;
        h[lg][r] = hn;
        o += wdv[lg][r] * hn;
      }
    o += __shfl_xor(o, 16, 64);
    o += __shfl_xor(o, 32, 64);
    if (half == 1 && L < 16) obuf[grp][L] = o;
    // (6) pack this half's h for next step
    if (t < T_ - 1) {
#pragma unroll
      for (int lg = 0; lg < 2; lg++)
#pragma unroll
        for (int rp = 0; rp < 2; rp++) {
          uint32_t phi, plo;
          sp2(h[lg][2 * rp], h[lg][2 * rp + 1], phi, plo);
          int pidx = 8 * (h2 + lg) + 2 * q + rp;
          hxg[(pidx * 2 + 0) * 21 + c] = phi;
          hxg[(pidx * 2 + 1) * 21 + c] = plo;
        }
    }
    __syncthreads();                     // B: packs + obuf visible
    if (half == 0 && L < 16)
      out[(size_t)(b * T_ + t) * N_ + node0 + L] = o + obuf[grp][L] + bdv;
    curA = nxA; curB = nxB;
  }
}

extern "C" void kernel_launch(void* const* d_in, const int* in_sizes, int n_in,
                              void* d_out, int out_size, void* d_ws, size_t ws_size,
                              hipStream_t stream) {
  const float* x     = (const float*)d_in[0];
  const float* adj   = (const float*)d_in[1];
  const float* gamma = (const float*)d_in[2];
  const float* beta  = (const float*)d_in[3];
  const float* Wg    = (const float*)d_in[4];
  const float* bg    = (const float*)d_in[5];
  const float* Wih   = (const float*)d_in[6];
  const float* Whh   = (const float*)d_in[7];
  const float* bih   = (const float*)d_in[8];
  const float* bhh   = (const float*)d_in[9];
  const float* Wd    = (const float*)d_in[10];
  const float* bd    = (const float*)d_in[11];
  float* ws = (float*)d_ws;
  float* out = (float*)d_out;

  k_pre<<<2048 + 256, 256, 0, stream>>>(x, adj, ws);
  k_aggf<<<1024 + 52, 256, 0, stream>>>(x, gamma, beta, Wg, bg, Wih, bih, Whh, bhh, ws);
  k_gru<<<512, 256, 0, stream>>>(Wd, bd, ws, out);
}

// Round 6
// 176.770 us; speedup vs baseline: 1.0053x; 1.0053x over previous
//
#include <hip/hip_runtime.h>
#include <hip/hip_bf16.h>
#include <stdint.h>

#define B_ 4
#define T_ 8
#define N_ 4096
#define F_ 32
#define BT_ (B_*T_)
#define ROWS_ (B_*N_)
#define CAP_ 128
#define EPS_ 1e-5f
#define NELEM_ (B_*T_*N_*F_)

// ---- workspace layout (float offsets) ----
#define WS_BNP    0                       // 256 * 64 per-block BN partials
#define WS_ROWSUM 16384                   // 4096
#define WS_DEG    (WS_ROWSUM + 4096)      // 4096 (int)
#define WS_FRG    (WS_DEG + 4096)         // 52 frags * 64 lanes * 4 dwords
#define WS_PAIR   (WS_FRG + 52*256)       // 4096*CAP_*2  (idx*F_ as float-bits, val)
#define WS_XA     (WS_PAIR + 4096*CAP_*2) // BT_*N_*F_ floats
#define WS_X16    (WS_XA + NELEM_)        // BT_*N_*F_ halves (NELEM_/2 floats)

typedef float v4f __attribute__((ext_vector_type(4)));
typedef _Float16 half8 __attribute__((ext_vector_type(8)));
union HU { uint32_t u[4]; half8 v; };

__device__ inline float sigm_f(float x) {
  return __builtin_amdgcn_rcpf(1.0f + __expf(-x));
}
__device__ inline uint32_t f16pair(float a, float b) {
  union { _Float16 h; unsigned short s; } x, y;
  x.h = (_Float16)a; y.h = (_Float16)b;
  return (uint32_t)x.s | ((uint32_t)y.s << 16);
}
__device__ inline void sp2(float a0, float a1, uint32_t& hi, uint32_t& lo) {
  _Float16 h0 = (_Float16)a0, h1 = (_Float16)a1;
  float r0 = a0 - (float)h0, r1 = a1 - (float)h1;
  union { _Float16 h; unsigned short s; } u0, u1, v0, v1;
  u0.h = h0; u1.h = h1; v0.h = (_Float16)r0; v1.h = (_Float16)r1;
  hi = (uint32_t)u0.s | ((uint32_t)u1.s << 16);
  lo = (uint32_t)v0.s | ((uint32_t)v1.s << 16);
}

// ---- K1: CSR build, 2 rows/block (blocks 0..2047) + BN partials + f16-x
//      emission (blocks 2048..2303) ----
__global__ void __launch_bounds__(256)
k_pre(const float* __restrict__ x, const float* __restrict__ A, float* __restrict__ ws) {
  if (blockIdx.x < 2048) {
    int m0 = blockIdx.x * 2;
    __shared__ int cnt[2];
    __shared__ float wsum[4][2];
    if (threadIdx.x < 2) cnt[threadIdx.x] = 0;
    __syncthreads();
    int* deg = (int*)&ws[WS_DEG];
    float2* pair = (float2*)&ws[WS_PAIR];
    const float4* A4 = (const float4*)(A + (size_t)m0 * N_);
    float4 av4[8];
#pragma unroll
    for (int r = 0; r < 2; r++)
#pragma unroll
      for (int i = 0; i < 4; i++) av4[r * 4 + i] = A4[r * 1024 + threadIdx.x + 256 * i];  // 8 in flight
    float lsum[2] = {0.f, 0.f};
#pragma unroll
    for (int r = 0; r < 2; r++)
#pragma unroll
      for (int i = 0; i < 4; i++) {
        float av[4] = {av4[r*4+i].x, av4[r*4+i].y, av4[r*4+i].z, av4[r*4+i].w};
        int nb4 = (threadIdx.x + 256 * i) * 4;
#pragma unroll
        for (int e = 0; e < 4; e++) {
          float a = av[e];
          if (a != 0.0f) {
            int p = atomicAdd(&cnt[r], 1);
            if (p < CAP_) pair[(size_t)(m0 + r) * CAP_ + p] = make_float2(__int_as_float((nb4 + e) * F_), a);
            lsum[r] += a;
          }
        }
      }
#pragma unroll
    for (int r = 0; r < 2; r++) {
      float s = lsum[r];
#pragma unroll
      for (int off = 32; off > 0; off >>= 1) s += __shfl_xor(s, off, 64);
      if ((threadIdx.x & 63) == 0) wsum[threadIdx.x >> 6][r] = s;
    }
    __syncthreads();                     // cnt + wsum final
#pragma unroll
    for (int r = 0; r < 2; r++) {
      int c = cnt[r];
      for (int p = c + threadIdx.x; p < 68; p += 256)   // zero-fill incl. prefetch pad
        pair[(size_t)(m0 + r) * CAP_ + p] = make_float2(__int_as_float(0), 0.0f);
    }
    if (threadIdx.x < 2) {
      int r = threadIdx.x;
      deg[m0 + r] = min(cnt[r], CAP_);
      ws[WS_ROWSUM + m0 + r] = wsum[0][r] + wsum[1][r] + wsum[2][r] + wsum[3][r];
    }
  } else {
    int bnb = blockIdx.x - 2048;
    const float4* x4 = (const float4*)x;
    uint2* x16 = (uint2*)(ws + WS_X16);  // 4 halves per float4 slot
    int tid = bnb * 256 + threadIdx.x;
    float s[4] = {0,0,0,0}, s2[4] = {0,0,0,0};
    for (int i = tid; i < NELEM_ / 4; i += 256 * 256) {
      float4 v = x4[i];
      s[0] += v.x; s2[0] += v.x * v.x;
      s[1] += v.y; s2[1] += v.y * v.y;
      s[2] += v.z; s2[2] += v.z * v.z;
      s[3] += v.w; s2[3] += v.w * v.w;
      uint2 hp;
      hp.x = f16pair(v.x, v.y);
      hp.y = f16pair(v.z, v.w);
      x16[i] = hp;
    }
    __shared__ float ls[256][4], ls2[256][4];
#pragma unroll
    for (int r = 0; r < 4; r++) { ls[threadIdx.x][r] = s[r]; ls2[threadIdx.x][r] = s2[r]; }
    __syncthreads();
    int t = threadIdx.x;
    if (t < 32) {                       // channel c = 4*(q&7)+r
      int g = t >> 2, r = t & 3;
      float a = 0.f;
      for (int q = g; q < 256; q += 8) a += ls[q][r];
      ws[WS_BNP + bnb * 64 + t] = a;
    } else if (t < 64) {
      int cch = t - 32;
      int g = cch >> 2, r = cch & 3;
      float b2 = 0.f;
      for (int q = g; q < 256; q += 8) b2 += ls2[q][r];
      ws[WS_BNP + bnb * 64 + t] = b2;
    }
  }
}

// ---- K2: sparse aggregation from f16 x (half bytes, half requests).
//      Lane = (row, f8, sg): 4 lanes x 16B cover a 64B f16 row; each lane
//      owns 8 channels x 2 bt-slices. Blocks 0..1023 agg, 1024..1075 fold. ----
#define AGG_STEP(d) { \
    float vv = pv[d]; \
    half8 t0 = pb0[d], t1 = pb1[d]; \
    float2 p = pl[row * 69 + k + 4 + d]; \
    int off = __float_as_int(p.x) + fo; \
    pv[d] = p.y; \
    pb0[d] = *(const half8*)(xh0 + off); \
    pb1[d] = *(const half8*)(xh1 + off); \
    _Pragma("unroll") \
    for (int j = 0; j < 8; j++) { \
      acc0[j] += vv * (float)t0[j]; \
      acc1[j] += vv * (float)t1[j]; } }

__global__ void __launch_bounds__(256, 4)
k_aggf(const float* __restrict__ x, const float* __restrict__ gamma,
       const float* __restrict__ beta, const float* __restrict__ Wg,
       const float* __restrict__ bg, const float* __restrict__ Wih,
       const float* __restrict__ bih, const float* __restrict__ Whh,
       const float* __restrict__ bhh, float* __restrict__ ws) {
  __shared__ float2 pl[32 * 69];        // 17.7 KB (fold path overlays first 14.1 KB)
  int tid = threadIdx.x;
  if (blockIdx.x >= 1024) {
    // ================= fold path: build fragment fi =================
    float* fs   = (float*)pl;
    float* bnp4 = fs;                    // 256
    float* bns  = fs + 256;              // 64
    float* scl  = fs + 320;              // 32
    float* shf  = fs + 352;              // 32
    float* ps   = fs + 384;              // 32
    float* Wg_s = fs + 416;              // 1024
    float* Wic  = fs + 1440;             // 512  (Wih col-slice [32][16])
    float* Wxc  = fs + 1952;             // 512  (Wx col-slice  [32][16])
    float* UsV  = fs + 2464;             // 32   (Us[16], Vs[16])
    float* Whc  = fs + 2496;             // 512  (Whh col-slice [32][16])
    int fi = blockIdx.x - 1024;
    int mt, kt;
    if (fi < 32)      { mt = fi >> 2;              kt = fi & 3; }
    else if (fi < 40) { mt = 8 + ((fi - 32) >> 1); kt = (fi & 1) ? 3 : 0; }
    else              { int r = fi - 40; mt = 12 + r / 3; kt = 1 + r % 3; }
    int cls = mt >> 2;
    int colbase = (cls < 2) ? mt * 16 : 128 + (mt & 3) * 16;
    // ---- stage phase ----
    if (kt == 1 || kt == 2) {            // Whh rows [(kt-1)*32, (kt-1)*32+32), 16 cols
      for (int e = tid; e < 512; e += 256) {
        int r = e >> 4, cc = e & 15;
        Whc[e] = Whh[(size_t)((kt - 1) * 32 + r) * 192 + colbase + cc];
      }
    } else {                             // kt 0/3: Wg + Wih cols + BNP partial reduce
      ((float4*)Wg_s)[tid] = ((const float4*)Wg)[tid];
      for (int e = tid; e < 512; e += 256) {
        int r = e >> 4, cc = e & 15;
        Wic[e] = Wih[(size_t)r * 192 + colbase + cc];
      }
      int g = tid >> 6, cch = tid & 63;
      float a = 0.f;
      for (int i = 0; i < 64; i++) a += ws[WS_BNP + (size_t)(g + 4 * i) * 64 + cch];
      bnp4[g * 64 + cch] = a;
    }
    __syncthreads();
    if ((kt == 0 || kt == 3) && tid < 64)
      bns[tid] = bnp4[tid] + bnp4[64 + tid] + bnp4[128 + tid] + bnp4[192 + tid];
    __syncthreads();
    if ((kt == 0 || kt == 3) && tid < 32) {
      float cntf = (float)(B_ * T_ * N_);
      float mean = bns[tid] / cntf;
      float var = bns[32 + tid] / cntf - mean * mean;
      float sc = gamma[tid] * rsqrtf(var + EPS_);
      scl[tid] = sc;
      shf[tid] = beta[tid] - mean * sc;
    }
    __syncthreads();
    if (kt == 3 && tid < 32) {
      float acc = 0.f;
#pragma unroll
      for (int f = 0; f < 32; f++) acc += shf[f] * Wg_s[f * 32 + tid];
      ps[tid] = acc;
    }
    __syncthreads();
    if (kt == 0) {                       // Wx col-slice: scale[f] * (Wg row f · Wih col)
      for (int e = tid; e < 512; e += 256) {
        int f = e >> 4, cc = e & 15;
        float acc = 0.f;
#pragma unroll
        for (int m = 0; m < 32; m++) acc += Wg_s[f * 32 + m] * Wic[m * 16 + cc];
        Wxc[e] = scl[f] * acc;
      }
    } else if (kt == 3) {
      if (tid < 16) {
        float au = 0.f;
#pragma unroll
        for (int c2 = 0; c2 < 32; c2++) au += ps[c2] * Wic[c2 * 16 + tid];
        UsV[tid] = au;
      } else if (tid < 32) {
        int cc = tid - 16;
        float av = 0.f;
#pragma unroll
        for (int c2 = 0; c2 < 32; c2++) av += bg[c2] * Wic[c2 * 16 + cc];
        UsV[16 + cc] = av + bih[colbase + cc];
      }
    }
    __syncthreads();
    // ---- pack phase (64 lanes) ----
    if (tid < 64) {
      int L = tid, q = L >> 4, c = L & 15;
      uint32_t* wsu = (uint32_t*)ws;
#pragma unroll
      for (int d = 0; d < 4; d++) {
        float a01[2];
#pragma unroll
        for (int h2 = 0; h2 < 2; h2++) {
          int kk = q * 8 + 2 * d + h2;   // 0..31 within this kt block
          float v;
          if (kt == 0)       v = Wxc[kk * 16 + c];
          else if (kt != 3)  v = Whc[kk * 16 + c];
          else if (kk == 0)  v = (cls == 3) ? 0.f : UsV[c];
          else if (kk == 1)  v = (cls < 2) ? (UsV[16 + c] + bhh[colbase + c])
                                           : (cls == 2 ? UsV[16 + c] : bhh[colbase + c]);
          else               v = 0.f;
          a01[h2] = v;
        }
        wsu[WS_FRG + fi * 256 + L * 4 + d] = f16pair(a01[0], a01[1]);
      }
    }
    return;
  }
  // ================= aggregation path (f16 gather) =================
  int bid2 = blockIdx.x;
  int chunk = bid2 & 7;                 // 8 chunks of 4 bt; XCD = blockIdx%8 pins slices
  int mg = bid2 >> 3;                   // [0,128): 32-row group
  int row = (tid >> 2) & 31;            // 32 rows, 4 lanes each
  int f8 = tid & 3;                     // lane covers channels f8*8..f8*8+7
  int sg = tid >> 7;                    // slice-pair select: 0 -> {0,1}, 1 -> {2,3}
  int m = mg * 32 + row;
  const int* deg = (const int*)&ws[WS_DEG];
  const float2* pair = (const float2*)&ws[WS_PAIR];
  for (int qq = tid; qq < 32 * 68; qq += 256) {
    int r = qq / 68, sl = qq - r * 68;
    pl[r * 69 + sl] = pair[(size_t)(mg * 32 + r) * CAP_ + sl];
  }
  __syncthreads();
  int d0 = deg[m];
  int dm = min(d0, 64);
  int bound = dm;                       // wave-uniform max over the wave's 16 rows
  bound = max(bound, __shfl_xor(bound, 4, 64));
  bound = max(bound, __shfl_xor(bound, 8, 64));
  bound = max(bound, __shfl_xor(bound, 16, 64));
  bound = max(bound, __shfl_xor(bound, 32, 64));
  bound = (bound + 3) & ~3;             // mult of 4; slots < 68 valid/zeroed
  int bt0 = chunk * 4 + 2 * sg;
  const _Float16* xg = (const _Float16*)(ws + WS_X16);
  const _Float16* xh0 = xg + (size_t)bt0 * N_ * F_;
  const _Float16* xh1 = xh0 + N_ * F_;
  int fo = f8 * 8;
  float acc0[8], acc1[8];
#pragma unroll
  for (int j = 0; j < 8; j++) { acc0[j] = 0.f; acc1[j] = 0.f; }
  half8 pb0[4], pb1[4];
  float pv[4];
#pragma unroll
  for (int d = 0; d < 4; d++) {         // prologue: 8 loads in flight
    float2 p = pl[row * 69 + d];
    int off = __float_as_int(p.x) + fo;
    pv[d] = p.y;
    pb0[d] = *(const half8*)(xh0 + off);
    pb1[d] = *(const half8*)(xh1 + off);
  }
  for (int k = 0; k < bound; k += 4) {
    AGG_STEP(0) AGG_STEP(1) AGG_STEP(2) AGG_STEP(3)
  }
  if (d0 > 64) {                        // statistically never (avg deg ~32)
    for (int k = 64; k < d0; k++) {
      float2 p = pair[(size_t)m * CAP_ + k];
      int off = __float_as_int(p.x) + fo;
      float vv = p.y;
#pragma unroll
      for (int j = 0; j < 8; j++) {
        acc0[j] += vv * (float)xh0[off + j];
        acc1[j] += vv * (float)xh1[off + j];
      }
    }
  }
  size_t ob = (size_t)bt0 * N_ * F_ + m * F_ + fo;
  v4f s0a = {acc0[0], acc0[1], acc0[2], acc0[3]};
  v4f s0b = {acc0[4], acc0[5], acc0[6], acc0[7]};
  v4f s1a = {acc1[0], acc1[1], acc1[2], acc1[3]};
  v4f s1b = {acc1[4], acc1[5], acc1[6], acc1[7]};
  *(v4f*)(ws + WS_XA + ob) = s0a;
  *(v4f*)(ws + WS_XA + ob + 4) = s0b;
  *(v4f*)(ws + WS_XA + ob + (size_t)N_ * F_) = s1a;
  *(v4f*)(ws + WS_XA + ob + (size_t)N_ * F_ + 4) = s1b;
}

// ---- K4: MFMA GRU, gate-tile split across wave pairs -> 2 waves/SIMD. ----
#define LDA(fi) (*(const half8*)(frg + (fi)*256 + L*4))
#define DO1(A_, fi, BH, BL) { half8 af = LDA(fi); \
  A_ = __builtin_amdgcn_mfma_f32_16x16x32_f16(af, BH, A_, 0, 0, 0); \
  A_ = __builtin_amdgcn_mfma_f32_16x16x32_f16(af, BL, A_, 0, 0, 0); }
#define DO1C(A_, C_, fi, BH, BL) { half8 af = LDA(fi); \
  A_ = __builtin_amdgcn_mfma_f32_16x16x32_f16(af, BH, C_, 0, 0, 0); \
  A_ = __builtin_amdgcn_mfma_f32_16x16x32_f16(af, BL, A_, 0, 0, 0); }

__global__ void __launch_bounds__(256, 2)
k_gru(const float* __restrict__ Wd, const float* __restrict__ bd,
      const float* __restrict__ ws, float* __restrict__ out) {
  __shared__ uint32_t frg[52 * 256];     // 53 KB weight fragments (block-shared)
  __shared__ uint32_t hx[2 * 1344];      // per-GROUP h-exchange, stride 21
  __shared__ float obuf[2][16];          // cross-half output partial
  {
    const uint4* gf = (const uint4*)(ws + WS_FRG);
    uint4* sf = (uint4*)frg;
    for (int i = threadIdx.x; i < 52 * 64; i += 256) sf[i] = gf[i];
  }
  __syncthreads();
  int wid = threadIdx.x >> 6, L = threadIdx.x & 63;
  int grp = wid >> 1, half = wid & 1, h2 = half * 2;
  int q = L >> 4, c = L & 15;
  uint32_t* hxg = hx + grp * 1344;
  int rg0 = blockIdx.x * 32 + grp * 16;  // global row base of this group's 16-row tile
  int b = rg0 >> 12;
  int node0 = rg0 & (N_ - 1);
  // fragment indices for this half's tiles
  int fR0 = 4 * h2, fR1 = 4 * h2 + 4;          // R tiles: mt = h2, h2+1
  int fZ0 = 16 + 4 * h2, fZ1 = 20 + 4 * h2;    // Z tiles: mt = 4+h2, 5+h2
  int fN0 = 32 + 2 * h2, fN1 = 34 + 2 * h2;    // N tiles b0: mt = 8+h2, 9+h2
  int fG0 = 40 + 3 * h2, fG1 = 43 + 3 * h2;    // G tiles b1: mt = 12+h2, 13+h2
  float wdv[2][4];
#pragma unroll
  for (int lg = 0; lg < 2; lg++)
#pragma unroll
    for (int r = 0; r < 4; r++) wdv[lg][r] = Wd[16 * (h2 + lg) + 4 * q + r];
  float bdv = bd[0];

  // ---- b3 fragment (rowsum trick) ----
  HU b3h, b3l;
#pragma unroll
  for (int d = 0; d < 4; d++) { b3h.u[d] = 0; b3l.u[d] = 0; }
  {
    float rsv = ws[WS_ROWSUM + node0 + c];
    uint32_t rhi, rlo;
    sp2(rsv, 1.0f, rhi, rlo);
    if (q == 0) { b3h.u[0] = rhi; b3l.u[0] = rlo & 0xFFFFu; }
  }

  // ---- per-half time-invariant bias tiles (8 v4f) ----
  v4f bias[8];
  {
    v4f z4 = {0.f, 0.f, 0.f, 0.f};
    DO1C(bias[0], z4, fR0 + 3, b3h.v, b3l.v)
    DO1C(bias[1], z4, fR1 + 3, b3h.v, b3l.v)
    DO1C(bias[2], z4, fZ0 + 3, b3h.v, b3l.v)
    DO1C(bias[3], z4, fZ1 + 3, b3h.v, b3l.v)
    DO1C(bias[4], z4, fN0 + 1, b3h.v, b3l.v)
    DO1C(bias[5], z4, fN1 + 1, b3h.v, b3l.v)
    DO1C(bias[6], z4, fG0 + 2, b3h.v, b3l.v)
    DO1C(bias[7], z4, fG1 + 2, b3h.v, b3l.v)
  }

  float h[2][4];
#pragma unroll
  for (int lg = 0; lg < 2; lg++)
#pragma unroll
    for (int r = 0; r < 4; r++) h[lg][r] = 0.f;

  const float* xab = ws + WS_XA;
  size_t xo0 = ((size_t)(b * T_) * N_ + node0 + c) * F_ + q * 8;
  float4 curA = *(const float4*)(xab + xo0);
  float4 curB = *(const float4*)(xab + xo0 + 4);
  float4 nxA, nxB;

#pragma unroll 1
  for (int t = 0; t < T_; t++) {
    // (1) read h fragments packed at end of t-1 (group-shared)
    HU b1h, b1l, b2h, b2l;
    if (t > 0) {
#pragma unroll
      for (int d = 0; d < 4; d++) {
        b1h.u[d] = hxg[((4 * q + d) * 2 + 0) * 21 + c];
        b1l.u[d] = hxg[((4 * q + d) * 2 + 1) * 21 + c];
        b2h.u[d] = hxg[((16 + 4 * q + d) * 2 + 0) * 21 + c];
        b2l.u[d] = hxg[((16 + 4 * q + d) * 2 + 1) * 21 + c];
      }
    }
    __syncthreads();                     // A: all reads done before this step's writes
    // (2) prefetch next xa
    if (t < T_ - 1) {
      size_t xo = ((size_t)(b * T_ + t + 1) * N_ + node0 + c) * F_ + q * 8;
      nxA = *(const float4*)(xab + xo);
      nxB = *(const float4*)(xab + xo + 4);
    }
    // (3) build b0 fragment from current xa
    HU b0h, b0l;
    sp2(curA.x, curA.y, b0h.u[0], b0l.u[0]);
    sp2(curA.z, curA.w, b0h.u[1], b0l.u[1]);
    sp2(curB.x, curB.y, b0h.u[2], b0l.u[2]);
    sp2(curB.z, curB.w, b0h.u[3], b0l.u[3]);
    // (4) MFMAs for this half's 8 tiles
    v4f acc[8];
    if (t > 0) {
      DO1C(acc[0], bias[0], fR0 + 1, b1h.v, b1l.v)
      DO1C(acc[1], bias[1], fR1 + 1, b1h.v, b1l.v)
      DO1C(acc[2], bias[2], fZ0 + 1, b1h.v, b1l.v)
      DO1C(acc[3], bias[3], fZ1 + 1, b1h.v, b1l.v)
      DO1C(acc[6], bias[6], fG0,     b1h.v, b1l.v)
      DO1C(acc[7], bias[7], fG1,     b1h.v, b1l.v)
      DO1(acc[0], fR0 + 2, b2h.v, b2l.v)
      DO1(acc[1], fR1 + 2, b2h.v, b2l.v)
      DO1(acc[2], fZ0 + 2, b2h.v, b2l.v)
      DO1(acc[3], fZ1 + 2, b2h.v, b2l.v)
      DO1(acc[6], fG0 + 1, b2h.v, b2l.v)
      DO1(acc[7], fG1 + 1, b2h.v, b2l.v)
      DO1(acc[0], fR0, b0h.v, b0l.v)
      DO1(acc[1], fR1, b0h.v, b0l.v)
      DO1(acc[2], fZ0, b0h.v, b0l.v)
      DO1(acc[3], fZ1, b0h.v, b0l.v)
      DO1C(acc[4], bias[4], fN0, b0h.v, b0l.v)
      DO1C(acc[5], bias[5], fN1, b0h.v, b0l.v)
    } else {
      DO1C(acc[0], bias[0], fR0, b0h.v, b0l.v)
      DO1C(acc[1], bias[1], fR1, b0h.v, b0l.v)
      DO1C(acc[2], bias[2], fZ0, b0h.v, b0l.v)
      DO1C(acc[3], bias[3], fZ1, b0h.v, b0l.v)
      DO1C(acc[4], bias[4], fN0, b0h.v, b0l.v)
      DO1C(acc[5], bias[5], fN1, b0h.v, b0l.v)
      acc[6] = bias[6]; acc[7] = bias[7];
    }
    // (5) epilogue on this half's 32 hidden dims
    float o = 0.f;
#pragma unroll
    for (int lg = 0; lg < 2; lg++)
#pragma unroll
      for (int r = 0; r < 4; r++) {
        float rr = sigm_f(acc[lg][r]);
        float zz = sigm_f(acc[2 + lg][r]);
        float nn = 2.0f * sigm_f(2.0f * (acc[4 + lg][r] + rr * acc[6 + lg][r])) - 1.0f;
        float hn = zz * (h[lg][r] - nn) + nn;
        h[lg][r] = hn;
        o += wdv[lg][r] * hn;
      }
    o += __shfl_xor(o, 16, 64);
    o += __shfl_xor(o, 32, 64);
    if (half == 1 && L < 16) obuf[grp][L] = o;
    // (6) pack this half's h for next step
    if (t < T_ - 1) {
#pragma unroll
      for (int lg = 0; lg < 2; lg++)
#pragma unroll
        for (int rp = 0; rp < 2; rp++) {
          uint32_t phi, plo;
          sp2(h[lg][2 * rp], h[lg][2 * rp + 1], phi, plo);
          int pidx = 8 * (h2 + lg) + 2 * q + rp;
          hxg[(pidx * 2 + 0) * 21 + c] = phi;
          hxg[(pidx * 2 + 1) * 21 + c] = plo;
        }
    }
    __syncthreads();                     // B: packs + obuf visible
    if (half == 0 && L < 16)
      out[(size_t)(b * T_ + t) * N_ + node0 + L] = o + obuf[grp][L] + bdv;
    curA = nxA; curB = nxB;
  }
}

extern "C" void kernel_launch(void* const* d_in, const int* in_sizes, int n_in,
                              void* d_out, int out_size, void* d_ws, size_t ws_size,
                              hipStream_t stream) {
  const float* x     = (const float*)d_in[0];
  const float* adj   = (const float*)d_in[1];
  const float* gamma = (const float*)d_in[2];
  const float* beta  = (const float*)d_in[3];
  const float* Wg    = (const float*)d_in[4];
  const float* bg    = (const float*)d_in[5];
  const float* Wih   = (const float*)d_in[6];
  const float* Whh   = (const float*)d_in[7];
  const float* bih   = (const float*)d_in[8];
  const float* bhh   = (const float*)d_in[9];
  const float* Wd    = (const float*)d_in[10];
  const float* bd    = (const float*)d_in[11];
  float* ws = (float*)d_ws;
  float* out = (float*)d_out;

  k_pre<<<2048 + 256, 256, 0, stream>>>(x, adj, ws);
  k_aggf<<<1024 + 52, 256, 0, stream>>>(x, gamma, beta, Wg, bg, Wih, bih, Whh, bhh, ws);
  k_gru<<<512, 256, 0, stream>>>(Wd, bd, ws, out);
}

// Round 7
// 167.924 us; speedup vs baseline: 1.0583x; 1.0527x over previous
//
#include <hip/hip_runtime.h>
#include <hip/hip_bf16.h>
#include <stdint.h>

#define B_ 4
#define T_ 8
#define N_ 4096
#define F_ 32
#define BT_ (B_*T_)
#define ROWS_ (B_*N_)
#define CAP_ 128
#define EPS_ 1e-5f
#define NELEM_ (B_*T_*N_*F_)

// ---- workspace layout (float offsets) ----
#define WS_BNP    0                       // 256 * 64 per-block BN partials
#define WS_ROWSUM 16384                   // 4096
#define WS_DEG    (WS_ROWSUM + 4096)      // 4096 (int)
#define WS_FRG    (WS_DEG + 4096)         // 52 frags * 64 lanes * 4 dwords
#define WS_PAIR   (WS_FRG + 52*256)       // 4096*CAP_*2  (idx*F_ as float-bits, val)
#define WS_XA     (WS_PAIR + 4096*CAP_*2) // BT_*N_*F_ floats
#define WS_X16    (WS_XA + NELEM_)        // BT_*N_*F_ halves, TRANSPOSED [node][bt][F]

typedef float v4f __attribute__((ext_vector_type(4)));
typedef _Float16 half8 __attribute__((ext_vector_type(8)));
union HU { uint32_t u[4]; half8 v; };

__device__ inline float sigm_f(float x) {
  return __builtin_amdgcn_rcpf(1.0f + __expf(-x));
}
__device__ inline uint32_t f16pair(float a, float b) {
  union { _Float16 h; unsigned short s; } x, y;
  x.h = (_Float16)a; y.h = (_Float16)b;
  return (uint32_t)x.s | ((uint32_t)y.s << 16);
}
__device__ inline void sp2(float a0, float a1, uint32_t& hi, uint32_t& lo) {
  _Float16 h0 = (_Float16)a0, h1 = (_Float16)a1;
  float r0 = a0 - (float)h0, r1 = a1 - (float)h1;
  union { _Float16 h; unsigned short s; } u0, u1, v0, v1;
  u0.h = h0; u1.h = h1; v0.h = (_Float16)r0; v1.h = (_Float16)r1;
  hi = (uint32_t)u0.s | ((uint32_t)u1.s << 16);
  lo = (uint32_t)v0.s | ((uint32_t)v1.s << 16);
}

// ---- K1: CSR build, 2 rows/block (blocks 0..2047) + BN partials + f16-x
//      TRANSPOSED emission [node][bt][F] (blocks 2048..2303) ----
__global__ void __launch_bounds__(256)
k_pre(const float* __restrict__ x, const float* __restrict__ A, float* __restrict__ ws) {
  if (blockIdx.x < 2048) {
    int m0 = blockIdx.x * 2;
    __shared__ int cnt[2];
    __shared__ float wsum[4][2];
    if (threadIdx.x < 2) cnt[threadIdx.x] = 0;
    __syncthreads();
    int* deg = (int*)&ws[WS_DEG];
    float2* pair = (float2*)&ws[WS_PAIR];
    const float4* A4 = (const float4*)(A + (size_t)m0 * N_);
    float4 av4[8];
#pragma unroll
    for (int r = 0; r < 2; r++)
#pragma unroll
      for (int i = 0; i < 4; i++) av4[r * 4 + i] = A4[r * 1024 + threadIdx.x + 256 * i];  // 8 in flight
    float lsum[2] = {0.f, 0.f};
#pragma unroll
    for (int r = 0; r < 2; r++)
#pragma unroll
      for (int i = 0; i < 4; i++) {
        float av[4] = {av4[r*4+i].x, av4[r*4+i].y, av4[r*4+i].z, av4[r*4+i].w};
        int nb4 = (threadIdx.x + 256 * i) * 4;
#pragma unroll
        for (int e = 0; e < 4; e++) {
          float a = av[e];
          if (a != 0.0f) {
            int p = atomicAdd(&cnt[r], 1);
            if (p < CAP_) pair[(size_t)(m0 + r) * CAP_ + p] = make_float2(__int_as_float((nb4 + e) * F_), a);
            lsum[r] += a;
          }
        }
      }
#pragma unroll
    for (int r = 0; r < 2; r++) {
      float s = lsum[r];
#pragma unroll
      for (int off = 32; off > 0; off >>= 1) s += __shfl_xor(s, off, 64);
      if ((threadIdx.x & 63) == 0) wsum[threadIdx.x >> 6][r] = s;
    }
    __syncthreads();                     // cnt + wsum final
#pragma unroll
    for (int r = 0; r < 2; r++) {
      int c = cnt[r];
      for (int p = c + threadIdx.x; p < 68; p += 256)   // zero-fill incl. prefetch pad
        pair[(size_t)(m0 + r) * CAP_ + p] = make_float2(__int_as_float(0), 0.0f);
    }
    if (threadIdx.x < 2) {
      int r = threadIdx.x;
      deg[m0 + r] = min(cnt[r], CAP_);
      ws[WS_ROWSUM + m0 + r] = wsum[0][r] + wsum[1][r] + wsum[2][r] + wsum[3][r];
    }
  } else {
    int bnb = blockIdx.x - 2048;
    const float4* x4 = (const float4*)x;
    uint2* x16 = (uint2*)(ws + WS_X16);
    int tid = bnb * 256 + threadIdx.x;
    float s[4] = {0,0,0,0}, s2[4] = {0,0,0,0};
    for (int i = tid; i < NELEM_ / 4; i += 256 * 256) {
      float4 v = x4[i];
      s[0] += v.x; s2[0] += v.x * v.x;
      s[1] += v.y; s2[1] += v.y * v.y;
      s[2] += v.z; s2[2] += v.z * v.z;
      s[3] += v.w; s2[3] += v.w * v.w;
      // transpose: i = [bt][n][f4] -> x16T[n][bt][f4]
      int bt = i >> 15, rem = i & 32767, n = rem >> 3, f4 = rem & 7;
      uint2 hp;
      hp.x = f16pair(v.x, v.y);
      hp.y = f16pair(v.z, v.w);
      x16[(size_t)(n * 32 + bt) * 8 + f4] = hp;
    }
    __shared__ float ls[256][4], ls2[256][4];
#pragma unroll
    for (int r = 0; r < 4; r++) { ls[threadIdx.x][r] = s[r]; ls2[threadIdx.x][r] = s2[r]; }
    __syncthreads();
    int t = threadIdx.x;
    if (t < 32) {                       // channel c = 4*(q&7)+r
      int g = t >> 2, r = t & 3;
      float a = 0.f;
      for (int q = g; q < 256; q += 8) a += ls[q][r];
      ws[WS_BNP + bnb * 64 + t] = a;
    } else if (t < 64) {
      int cch = t - 32;
      int g = cch >> 2, r = cch & 3;
      float b2 = 0.f;
      for (int q = g; q < 256; q += 8) b2 += ls2[q][r];
      ws[WS_BNP + bnb * 64 + t] = b2;
    }
  }
}

// ---- K2: sparse aggregation, WAVE = ONE ROW, lanes cover all 32 bt-slices
//      of the gathered node (2 KB contiguous, 2 coalesced 1-KB wave-loads
//      per edge). Blocks 0..1023 agg (4 rows each), 1024..1075 fold. ----
#define AGG_STEP(d) { \
    float vv = pv[d]; \
    half8 t0 = pb0[d], t1 = pb1[d]; \
    float2 p = pl[wid * 69 + k + 4 + d]; \
    int nb = __float_as_int(p.x) << 5; \
    pv[d] = p.y; \
    pb0[d] = *(const half8*)(xT + nb + lo0); \
    pb1[d] = *(const half8*)(xT + nb + lo1); \
    _Pragma("unroll") \
    for (int j = 0; j < 8; j++) { \
      acc0[j] += vv * (float)t0[j]; \
      acc1[j] += vv * (float)t1[j]; } }

__global__ void __launch_bounds__(256, 4)
k_aggf(const float* __restrict__ x, const float* __restrict__ gamma,
       const float* __restrict__ beta, const float* __restrict__ Wg,
       const float* __restrict__ bg, const float* __restrict__ Wih,
       const float* __restrict__ bih, const float* __restrict__ Whh,
       const float* __restrict__ bhh, float* __restrict__ ws) {
  __shared__ float2 pl[32 * 69];        // fold path overlays first 14.1 KB
  int tid = threadIdx.x;
  if (blockIdx.x >= 1024) {
    // ================= fold path: build fragment fi =================
    float* fs   = (float*)pl;
    float* bnp4 = fs;                    // 256
    float* bns  = fs + 256;              // 64
    float* scl  = fs + 320;              // 32
    float* shf  = fs + 352;              // 32
    float* ps   = fs + 384;              // 32
    float* Wg_s = fs + 416;              // 1024
    float* Wic  = fs + 1440;             // 512  (Wih col-slice [32][16])
    float* Wxc  = fs + 1952;             // 512  (Wx col-slice  [32][16])
    float* UsV  = fs + 2464;             // 32   (Us[16], Vs[16])
    float* Whc  = fs + 2496;             // 512  (Whh col-slice [32][16])
    int fi = blockIdx.x - 1024;
    int mt, kt;
    if (fi < 32)      { mt = fi >> 2;              kt = fi & 3; }
    else if (fi < 40) { mt = 8 + ((fi - 32) >> 1); kt = (fi & 1) ? 3 : 0; }
    else              { int r = fi - 40; mt = 12 + r / 3; kt = 1 + r % 3; }
    int cls = mt >> 2;
    int colbase = (cls < 2) ? mt * 16 : 128 + (mt & 3) * 16;
    // ---- stage phase ----
    if (kt == 1 || kt == 2) {            // Whh rows [(kt-1)*32, (kt-1)*32+32), 16 cols
      for (int e = tid; e < 512; e += 256) {
        int r = e >> 4, cc = e & 15;
        Whc[e] = Whh[(size_t)((kt - 1) * 32 + r) * 192 + colbase + cc];
      }
    } else {                             // kt 0/3: Wg + Wih cols + BNP partial reduce
      ((float4*)Wg_s)[tid] = ((const float4*)Wg)[tid];
      for (int e = tid; e < 512; e += 256) {
        int r = e >> 4, cc = e & 15;
        Wic[e] = Wih[(size_t)r * 192 + colbase + cc];
      }
      int g = tid >> 6, cch = tid & 63;
      float a = 0.f;
      for (int i = 0; i < 64; i++) a += ws[WS_BNP + (size_t)(g + 4 * i) * 64 + cch];
      bnp4[g * 64 + cch] = a;
    }
    __syncthreads();
    if ((kt == 0 || kt == 3) && tid < 64)
      bns[tid] = bnp4[tid] + bnp4[64 + tid] + bnp4[128 + tid] + bnp4[192 + tid];
    __syncthreads();
    if ((kt == 0 || kt == 3) && tid < 32) {
      float cntf = (float)(B_ * T_ * N_);
      float mean = bns[tid] / cntf;
      float var = bns[32 + tid] / cntf - mean * mean;
      float sc = gamma[tid] * rsqrtf(var + EPS_);
      scl[tid] = sc;
      shf[tid] = beta[tid] - mean * sc;
    }
    __syncthreads();
    if (kt == 3 && tid < 32) {
      float acc = 0.f;
#pragma unroll
      for (int f = 0; f < 32; f++) acc += shf[f] * Wg_s[f * 32 + tid];
      ps[tid] = acc;
    }
    __syncthreads();
    if (kt == 0) {                       // Wx col-slice: scale[f] * (Wg row f · Wih col)
      for (int e = tid; e < 512; e += 256) {
        int f = e >> 4, cc = e & 15;
        float acc = 0.f;
#pragma unroll
        for (int m = 0; m < 32; m++) acc += Wg_s[f * 32 + m] * Wic[m * 16 + cc];
        Wxc[e] = scl[f] * acc;
      }
    } else if (kt == 3) {
      if (tid < 16) {
        float au = 0.f;
#pragma unroll
        for (int c2 = 0; c2 < 32; c2++) au += ps[c2] * Wic[c2 * 16 + tid];
        UsV[tid] = au;
      } else if (tid < 32) {
        int cc = tid - 16;
        float av = 0.f;
#pragma unroll
        for (int c2 = 0; c2 < 32; c2++) av += bg[c2] * Wic[c2 * 16 + cc];
        UsV[16 + cc] = av + bih[colbase + cc];
      }
    }
    __syncthreads();
    // ---- pack phase (64 lanes) ----
    if (tid < 64) {
      int L = tid, q = L >> 4, c = L & 15;
      uint32_t* wsu = (uint32_t*)ws;
#pragma unroll
      for (int d = 0; d < 4; d++) {
        float a01[2];
#pragma unroll
        for (int h2 = 0; h2 < 2; h2++) {
          int kk = q * 8 + 2 * d + h2;   // 0..31 within this kt block
          float v;
          if (kt == 0)       v = Wxc[kk * 16 + c];
          else if (kt != 3)  v = Whc[kk * 16 + c];
          else if (kk == 0)  v = (cls == 3) ? 0.f : UsV[c];
          else if (kk == 1)  v = (cls < 2) ? (UsV[16 + c] + bhh[colbase + c])
                                           : (cls == 2 ? UsV[16 + c] : bhh[colbase + c]);
          else               v = 0.f;
          a01[h2] = v;
        }
        wsu[WS_FRG + fi * 256 + L * 4 + d] = f16pair(a01[0], a01[1]);
      }
    }
    return;
  }
  // ================= aggregation path (node-major f16 gather) =================
  int m0 = blockIdx.x * 4;              // 4 rows per block, one per wave
  int wid = tid >> 6, L = tid & 63;
  int m = m0 + wid;
  const int* deg = (const int*)&ws[WS_DEG];
  const float2* pair = (const float2*)&ws[WS_PAIR];
  for (int qq = tid; qq < 4 * 68; qq += 256) {
    int r = qq / 68, sl = qq - r * 68;
    pl[r * 69 + sl] = pair[(size_t)(m0 + r) * CAP_ + sl];
  }
  __syncthreads();
  int d0 = deg[m];                      // wave-uniform (whole wave = one row)
  int dm = min(d0, 64);
  int bound = (dm + 3) & ~3;            // mult of 4; slots < 68 valid/zeroed
  const _Float16* xT = (const _Float16*)(ws + WS_X16);
  int lo0 = L * 8, lo1 = 512 + L * 8;   // halves: [0,512) = slices 0..15, [512,1024) = 16..31
  float acc0[8], acc1[8];
#pragma unroll
  for (int j = 0; j < 8; j++) { acc0[j] = 0.f; acc1[j] = 0.f; }
  half8 pb0[4], pb1[4];
  float pv[4];
#pragma unroll
  for (int d = 0; d < 4; d++) {         // prologue: 8 coalesced 1-KB loads in flight
    float2 p = pl[wid * 69 + d];
    int nb = __float_as_int(p.x) << 5;  // (node*F_)*32 = node*1024 halves
    pv[d] = p.y;
    pb0[d] = *(const half8*)(xT + nb + lo0);
    pb1[d] = *(const half8*)(xT + nb + lo1);
  }
  for (int k = 0; k < bound; k += 4) {
    AGG_STEP(0) AGG_STEP(1) AGG_STEP(2) AGG_STEP(3)
  }
  if (d0 > 64) {                        // statistically never (avg deg ~32)
    for (int k = 64; k < d0; k++) {
      float2 p = pair[(size_t)m * CAP_ + k];
      int nb = __float_as_int(p.x) << 5;
      float vv = p.y;
      half8 t0 = *(const half8*)(xT + nb + lo0);
      half8 t1 = *(const half8*)(xT + nb + lo1);
#pragma unroll
      for (int j = 0; j < 8; j++) {
        acc0[j] += vv * (float)t0[j];
        acc1[j] += vv * (float)t1[j];
      }
    }
  }
  // lane L holds slices (L>>2) and (L>>2)+16, channels (L&3)*8 .. +7
  int s0 = L >> 2, cg = (L & 3) * 8;
  size_t ob0 = ((size_t)s0 * N_ + m) * F_ + cg;
  size_t ob1 = ((size_t)(s0 + 16) * N_ + m) * F_ + cg;
  v4f w0a = {acc0[0], acc0[1], acc0[2], acc0[3]};
  v4f w0b = {acc0[4], acc0[5], acc0[6], acc0[7]};
  v4f w1a = {acc1[0], acc1[1], acc1[2], acc1[3]};
  v4f w1b = {acc1[4], acc1[5], acc1[6], acc1[7]};
  *(v4f*)(ws + WS_XA + ob0) = w0a;
  *(v4f*)(ws + WS_XA + ob0 + 4) = w0b;
  *(v4f*)(ws + WS_XA + ob1) = w1a;
  *(v4f*)(ws + WS_XA + ob1 + 4) = w1b;
}

// ---- K4: MFMA GRU, gate-tile split across wave pairs -> 2 waves/SIMD. ----
#define LDA(fi) (*(const half8*)(frg + (fi)*256 + L*4))
#define DO1(A_, fi, BH, BL) { half8 af = LDA(fi); \
  A_ = __builtin_amdgcn_mfma_f32_16x16x32_f16(af, BH, A_, 0, 0, 0); \
  A_ = __builtin_amdgcn_mfma_f32_16x16x32_f16(af, BL, A_, 0, 0, 0); }
#define DO1C(A_, C_, fi, BH, BL) { half8 af = LDA(fi); \
  A_ = __builtin_amdgcn_mfma_f32_16x16x32_f16(af, BH, C_, 0, 0, 0); \
  A_ = __builtin_amdgcn_mfma_f32_16x16x32_f16(af, BL, A_, 0, 0, 0); }

__global__ void __launch_bounds__(256, 2)
k_gru(const float* __restrict__ Wd, const float* __restrict__ bd,
      const float* __restrict__ ws, float* __restrict__ out) {
  __shared__ uint32_t frg[52 * 256];     // 53 KB weight fragments (block-shared)
  __shared__ uint32_t hx[2 * 1344];      // per-GROUP h-exchange, stride 21
  __shared__ float obuf[2][16];          // cross-half output partial
  {
    const uint4* gf = (const uint4*)(ws + WS_FRG);
    uint4* sf = (uint4*)frg;
    for (int i = threadIdx.x; i < 52 * 64; i += 256) sf[i] = gf[i];
  }
  __syncthreads();
  int wid = threadIdx.x >> 6, L = threadIdx.x & 63;
  int grp = wid >> 1, half = wid & 1, h2 = half * 2;
  int q = L >> 4, c = L & 15;
  uint32_t* hxg = hx + grp * 1344;
  int rg0 = blockIdx.x * 32 + grp * 16;  // global row base of this group's 16-row tile
  int b = rg0 >> 12;
  int node0 = rg0 & (N_ - 1);
  // fragment indices for this half's tiles
  int fR0 = 4 * h2, fR1 = 4 * h2 + 4;          // R tiles: mt = h2, h2+1
  int fZ0 = 16 + 4 * h2, fZ1 = 20 + 4 * h2;    // Z tiles: mt = 4+h2, 5+h2
  int fN0 = 32 + 2 * h2, fN1 = 34 + 2 * h2;    // N tiles b0: mt = 8+h2, 9+h2
  int fG0 = 40 + 3 * h2, fG1 = 43 + 3 * h2;    // G tiles b1: mt = 12+h2, 13+h2
  float wdv[2][4];
#pragma unroll
  for (int lg = 0; lg < 2; lg++)
#pragma unroll
    for (int r = 0; r < 4; r++) wdv[lg][r] = Wd[16 * (h2 + lg) + 4 * q + r];
  float bdv = bd[0];

  // ---- b3 fragment (rowsum trick) ----
  HU b3h, b3l;
#pragma unroll
  for (int d = 0; d < 4; d++) { b3h.u[d] = 0; b3l.u[d] = 0; }
  {
    float rsv = ws[WS_ROWSUM + node0 + c];
    uint32_t rhi, rlo;
    sp2(rsv, 1.0f, rhi, rlo);
    if (q == 0) { b3h.u[0] = rhi; b3l.u[0] = rlo & 0xFFFFu; }
  }

  // ---- per-half time-invariant bias tiles (8 v4f) ----
  v4f bias[8];
  {
    v4f z4 = {0.f, 0.f, 0.f, 0.f};
    DO1C(bias[0], z4, fR0 + 3, b3h.v, b3l.v)
    DO1C(bias[1], z4, fR1 + 3, b3h.v, b3l.v)
    DO1C(bias[2], z4, fZ0 + 3, b3h.v, b3l.v)
    DO1C(bias[3], z4, fZ1 + 3, b3h.v, b3l.v)
    DO1C(bias[4], z4, fN0 + 1, b3h.v, b3l.v)
    DO1C(bias[5], z4, fN1 + 1, b3h.v, b3l.v)
    DO1C(bias[6], z4, fG0 + 2, b3h.v, b3l.v)
    DO1C(bias[7], z4, fG1 + 2, b3h.v, b3l.v)
  }

  float h[2][4];
#pragma unroll
  for (int lg = 0; lg < 2; lg++)
#pragma unroll
    for (int r = 0; r < 4; r++) h[lg][r] = 0.f;

  const float* xab = ws + WS_XA;
  size_t xo0 = ((size_t)(b * T_) * N_ + node0 + c) * F_ + q * 8;
  float4 curA = *(const float4*)(xab + xo0);
  float4 curB = *(const float4*)(xab + xo0 + 4);
  float4 nxA, nxB;

#pragma unroll 1
  for (int t = 0; t < T_; t++) {
    // (1) read h fragments packed at end of t-1 (group-shared)
    HU b1h, b1l, b2h, b2l;
    if (t > 0) {
#pragma unroll
      for (int d = 0; d < 4; d++) {
        b1h.u[d] = hxg[((4 * q + d) * 2 + 0) * 21 + c];
        b1l.u[d] = hxg[((4 * q + d) * 2 + 1) * 21 + c];
        b2h.u[d] = hxg[((16 + 4 * q + d) * 2 + 0) * 21 + c];
        b2l.u[d] = hxg[((16 + 4 * q + d) * 2 + 1) * 21 + c];
      }
    }
    __syncthreads();                     // A: all reads done before this step's writes
    // (2) prefetch next xa
    if (t < T_ - 1) {
      size_t xo = ((size_t)(b * T_ + t + 1) * N_ + node0 + c) * F_ + q * 8;
      nxA = *(const float4*)(xab + xo);
      nxB = *(const float4*)(xab + xo + 4);
    }
    // (3) build b0 fragment from current xa
    HU b0h, b0l;
    sp2(curA.x, curA.y, b0h.u[0], b0l.u[0]);
    sp2(curA.z, curA.w, b0h.u[1], b0l.u[1]);
    sp2(curB.x, curB.y, b0h.u[2], b0l.u[2]);
    sp2(curB.z, curB.w, b0h.u[3], b0l.u[3]);
    // (4) MFMAs for this half's 8 tiles
    v4f acc[8];
    if (t > 0) {
      DO1C(acc[0], bias[0], fR0 + 1, b1h.v, b1l.v)
      DO1C(acc[1], bias[1], fR1 + 1, b1h.v, b1l.v)
      DO1C(acc[2], bias[2], fZ0 + 1, b1h.v, b1l.v)
      DO1C(acc[3], bias[3], fZ1 + 1, b1h.v, b1l.v)
      DO1C(acc[6], bias[6], fG0,     b1h.v, b1l.v)
      DO1C(acc[7], bias[7], fG1,     b1h.v, b1l.v)
      DO1(acc[0], fR0 + 2, b2h.v, b2l.v)
      DO1(acc[1], fR1 + 2, b2h.v, b2l.v)
      DO1(acc[2], fZ0 + 2, b2h.v, b2l.v)
      DO1(acc[3], fZ1 + 2, b2h.v, b2l.v)
      DO1(acc[6], fG0 + 1, b2h.v, b2l.v)
      DO1(acc[7], fG1 + 1, b2h.v, b2l.v)
      DO1(acc[0], fR0, b0h.v, b0l.v)
      DO1(acc[1], fR1, b0h.v, b0l.v)
      DO1(acc[2], fZ0, b0h.v, b0l.v)
      DO1(acc[3], fZ1, b0h.v, b0l.v)
      DO1C(acc[4], bias[4], fN0, b0h.v, b0l.v)
      DO1C(acc[5], bias[5], fN1, b0h.v, b0l.v)
    } else {
      DO1C(acc[0], bias[0], fR0, b0h.v, b0l.v)
      DO1C(acc[1], bias[1], fR1, b0h.v, b0l.v)
      DO1C(acc[2], bias[2], fZ0, b0h.v, b0l.v)
      DO1C(acc[3], bias[3], fZ1, b0h.v, b0l.v)
      DO1C(acc[4], bias[4], fN0, b0h.v, b0l.v)
      DO1C(acc[5], bias[5], fN1, b0h.v, b0l.v)
      acc[6] = bias[6]; acc[7] = bias[7];
    }
    // (5) epilogue on this half's 32 hidden dims
    float o = 0.f;
#pragma unroll
    for (int lg = 0; lg < 2; lg++)
#pragma unroll
      for (int r = 0; r < 4; r++) {
        float rr = sigm_f(acc[lg][r]);
        float zz = sigm_f(acc[2 + lg][r]);
        float nn = 2.0f * sigm_f(2.0f * (acc[4 + lg][r] + rr * acc[6 + lg][r])) - 1.0f;
        float hn = zz * (h[lg][r] - nn) + nn;
        h[lg][r] = hn;
        o += wdv[lg][r] * hn;
      }
    o += __shfl_xor(o, 16, 64);
    o += __shfl_xor(o, 32, 64);
    if (half == 1 && L < 16) obuf[grp][L] = o;
    // (6) pack this half's h for next step
    if (t < T_ - 1) {
#pragma unroll
      for (int lg = 0; lg < 2; lg++)
#pragma unroll
        for (int rp = 0; rp < 2; rp++) {
          uint32_t phi, plo;
          sp2(h[lg][2 * rp], h[lg][2 * rp + 1], phi, plo);
          int pidx = 8 * (h2 + lg) + 2 * q + rp;
          hxg[(pidx * 2 + 0) * 21 + c] = phi;
          hxg[(pidx * 2 + 1) * 21 + c] = plo;
        }
    }
    __syncthreads();                     // B: packs + obuf visible
    if (half == 0 && L < 16)
      out[(size_t)(b * T_ + t) * N_ + node0 + L] = o + obuf[grp][L] + bdv;
    curA = nxA; curB = nxB;
  }
}

extern "C" void kernel_launch(void* const* d_in, const int* in_sizes, int n_in,
                              void* d_out, int out_size, void* d_ws, size_t ws_size,
                              hipStream_t stream) {
  const float* x     = (const float*)d_in[0];
  const float* adj   = (const float*)d_in[1];
  const float* gamma = (const float*)d_in[2];
  const float* beta  = (const float*)d_in[3];
  const float* Wg    = (const float*)d_in[4];
  const float* bg    = (const float*)d_in[5];
  const float* Wih   = (const float*)d_in[6];
  const float* Whh   = (const float*)d_in[7];
  const float* bih   = (const float*)d_in[8];
  const float* bhh   = (const float*)d_in[9];
  const float* Wd    = (const float*)d_in[10];
  const float* bd    = (const float*)d_in[11];
  float* ws = (float*)d_ws;
  float* out = (float*)d_out;

  k_pre<<<2048 + 256, 256, 0, stream>>>(x, adj, ws);
  k_aggf<<<1024 + 52, 256, 0, stream>>>(x, gamma, beta, Wg, bg, Wih, bih, Whh, bhh, ws);
  k_gru<<<512, 256, 0, stream>>>(Wd, bd, ws, out);
}